// Round 12
// baseline (149.679 us; speedup 1.0000x reference)
//
#include <hip/hip_runtime.h>
#include <hip/hip_bf16.h>

#define BATCH 64
#define IN_CH 128
#define ILEN  512
#define OLEN  505
#define OCH   128
#define KDIM  1024    // IN_CH * 8
#define BK    64      // K per chunk
#define NCHK  16      // KDIM / BK
#define NWG   OLEN

typedef float  f32x4  __attribute__((ext_vector_type(4)));
typedef short  bf16x8 __attribute__((ext_vector_type(8)));
typedef unsigned short u16x8 __attribute__((ext_vector_type(8)));
typedef u16x8 u16x8a __attribute__((aligned(4)));

__device__ __forceinline__ unsigned short f2bf(float f) {
  union { __hip_bfloat16 h; unsigned short s; } u;
  u.h = __float2bfloat16(f);
  return u.s;
}

// ---- pre-pass: x fp32 -> bf16 dual-shifted copies (R11-verified) ----
// xbe[row][t] = bf16(x[row][t]); xbo[row][t] = bf16(x[row][t+1])
__global__ __launch_bounds__(256) void lc1d_cvt(const float* __restrict__ x,
                                                unsigned short* __restrict__ xbe,
                                                unsigned short* __restrict__ xbo) {
  const int gid = blockIdx.x * 256 + threadIdx.x;
  const int row = gid >> 6;
  const int t8  = (gid & 63) << 3;
  const float* src = x + (size_t)row * ILEN + t8;
  const f32x4 v0 = *reinterpret_cast<const f32x4*>(src);
  const f32x4 v1 = *reinterpret_cast<const f32x4*>(src + 4);
  const float e8 = (t8 + 8 < ILEN) ? src[8] : 0.f;
  u16x8 e, o;
#pragma unroll
  for (int j = 0; j < 4; ++j) { e[j] = f2bf(v0[j]); e[4 + j] = f2bf(v1[j]); }
  o[0] = e[1]; o[1] = e[2]; o[2] = e[3];
  o[3] = e[4]; o[4] = e[5]; o[5] = e[6]; o[6] = e[7];
  o[7] = f2bf(e8);
  *reinterpret_cast<u16x8*>(xbe + (size_t)row * ILEN + t8) = e;
  *reinterpret_cast<u16x8*>(xbo + (size_t)row * ILEN + t8) = o;
}

// ---- main: B via gload_lds dbuf (R8-verified); A DIRECT global->reg ----
// Theory: A out of LDS cuts consume ds_reads 24->8/thread/iter, unstarving
// the LDS-DMA writes whose delayed retirement stalled every prior round.
template <bool USE_TMP>
__global__ __launch_bounds__(256, 2) void lc1d_main(
    const unsigned short* __restrict__ xbe, const unsigned short* __restrict__ xbo,
    const float* __restrict__ w, const float* __restrict__ bias,
    float* __restrict__ outp) {
  const int orig = blockIdx.x;
  const int xcd = orig & 7, idx = orig >> 3;
  const int q = NWG / 8, rm = NWG % 8;
  const int l = (xcd < rm ? xcd * (q + 1) : rm * (q + 1) + (xcd - rm) * q) + idx;

  const int tid  = threadIdx.x;
  const int lane = tid & 63;
  const int wn   = tid >> 6;
  const int r    = lane & 15;
  const int h    = lane >> 4;

  __shared__ float Bs[2][2][BK * 64];   // 64 KB (R8-verified layout+swizzle)

  f32x4 acc[2][4];
#pragma unroll
  for (int oh = 0; oh < 2; ++oh)
#pragma unroll
    for (int m = 0; m < 4; ++m) acc[oh][m] = (f32x4){0.f, 0.f, 0.f, 0.f};

  const float* __restrict__ wl = w + (size_t)l * (OCH * KDIM);
  const unsigned short* __restrict__ xw =
      ((l & 1) ? xbo : xbe) + (size_t)(l & ~1);

  // B staging map (R8-verbatim)
  const int so  = tid >> 4;
  const int sc  = tid & 15;
  const int ssw = ((so & 7) << 1) | ((so >> 3) & 1);

  auto stageB = [&](int buf, int kc, int oh) {
    const float* wo = wl + (size_t)oh * 64 * KDIM;
#pragma unroll
    for (int it = 0; it < 4; ++it) {
      const int ob = it * 16 + so;
      const float* src = wo + (size_t)ob * KDIM + kc * BK + (sc ^ ssw) * 4;
      __builtin_amdgcn_global_load_lds(
          (const __attribute__((address_space(1))) void*)src,
          (__attribute__((address_space(3))) void*)&Bs[buf][oh][ob * 64 + sc * 4],
          16, 0, 0);
    }
  };

  // A fragments direct to regs: frag(mt,ks) = xw[((mt*16+r)*IN_CH + kc*8 + ks*4 + h)*ILEN .. +8]
  // parity double-buffered (paE/paO); kc fully unrolled -> static indexing
  u16x8 paE[4][2], paO[4][2];
  const unsigned short* __restrict__ xbase =
      xw + (size_t)(r * IN_CH + h) * ILEN;   // + mt*16*IN_CH*ILEN + (kc*8+ks*4)*ILEN

  auto prefA = [&](u16x8 (&pa)[4][2], int kc) {
#pragma unroll
    for (int mt = 0; mt < 4; ++mt) {
      const unsigned short* p =
          xbase + (size_t)(mt * 16 * IN_CH + kc * 8) * ILEN;
      pa[mt][0] = *reinterpret_cast<const u16x8a*>(p);
      pa[mt][1] = *reinterpret_cast<const u16x8a*>(p + 4 * ILEN);
    }
  };

  const int rsw = ((r & 7) << 1) | ((r >> 3) & 1);
  auto compute = [&](int cur, u16x8 (&pa)[4][2], int oh) {
    const int ob = wn * 16 + r;
#pragma unroll
    for (int ks = 0; ks < 2; ++ks) {
      const int c0 = ks * 8 + h * 2;
      const f32x4 blo = *reinterpret_cast<const f32x4*>(
          &Bs[cur][oh][ob * 64 + ((c0) ^ rsw) * 4]);
      const f32x4 bhi = *reinterpret_cast<const f32x4*>(
          &Bs[cur][oh][ob * 64 + ((c0 + 1) ^ rsw) * 4]);
      bf16x8 bfr;
#pragma unroll
      for (int j = 0; j < 4; ++j) {
        bfr[j]     = (short)f2bf(blo[j]);
        bfr[4 + j] = (short)f2bf(bhi[j]);
      }
#pragma unroll
      for (int mt = 0; mt < 4; ++mt) {
        const bf16x8 afr = (bf16x8)pa[mt][ks];
        acc[oh][mt] =
            __builtin_amdgcn_mfma_f32_16x16x32_bf16(afr, bfr, acc[oh][mt], 0, 0, 0);
      }
    }
  };

  // ---- prologue: B8(0) staged, A8(0) -> paE (flying; auto-waited at use) ----
  stageB(0, 0, 0);
  stageB(0, 0, 1);
  prefA(paE, 0);
  asm volatile("s_waitcnt vmcnt(8)" ::: "memory");   // retires B8(0) only
  __builtin_amdgcn_sched_barrier(0);
  __builtin_amdgcn_s_barrier();
  __builtin_amdgcn_sched_barrier(0);

#pragma unroll
  for (int kc = 0; kc < NCHK; ++kc) {
    const int cur = kc & 1, nxt = cur ^ 1;
    if (kc + 1 < NCHK) {
      stageB(nxt, kc + 1, 0);          // B8(kc+1): oldest of this iter's issues
      stageB(nxt, kc + 1, 1);
      if ((kc & 1) == 0) prefA(paO, kc + 1); else prefA(paE, kc + 1);
    }
    __builtin_amdgcn_sched_barrier(0);
    // compiler auto-inserts vmcnt(16) before first pa use (A8(kc) oldest)
    if ((kc & 1) == 0) { compute(cur, paE, 0); compute(cur, paE, 1); }
    else               { compute(cur, paO, 0); compute(cur, paO, 1); }
    if (kc + 1 < NCHK) {
      // outstanding: B8(kc+1)+A8(kc+1)=16 -> vmcnt(8) retires B8(kc+1) exactly
      asm volatile("s_waitcnt vmcnt(8) lgkmcnt(0)" ::: "memory");
      __builtin_amdgcn_sched_barrier(0);
      __builtin_amdgcn_s_barrier();
      __builtin_amdgcn_sched_barrier(0);
    }
  }

  // ---- epilogue (R8-verbatim): C/D col(o)=lane&15, row(b)=(lane>>4)*4+j ----
#pragma unroll
  for (int oh = 0; oh < 2; ++oh) {
    const int og = oh * 64 + wn * 16 + r;
    if (USE_TMP) {
      float* t = outp + (size_t)l * (BATCH * OCH) + og;
#pragma unroll
      for (int mt = 0; mt < 4; ++mt)
#pragma unroll
        for (int j = 0; j < 4; ++j) {
          const int b = mt * 16 + h * 4 + j;
          t[(size_t)b * OCH] = acc[oh][mt][j];
        }
    } else {
      const float bv = bias[og * OLEN + l];
#pragma unroll
      for (int mt = 0; mt < 4; ++mt)
#pragma unroll
        for (int j = 0; j < 4; ++j) {
          const int b = mt * 16 + h * 4 + j;
          outp[(size_t)b * (OCH * OLEN) + (size_t)og * OLEN + l] = acc[oh][mt][j] + bv;
        }
    }
  }
}

// tmp[l][b][o] -> out[b][o][l] (+bias)
__global__ __launch_bounds__(256) void lc1d_tr(const float* __restrict__ tmp,
                                               const float* __restrict__ bias,
                                               float* __restrict__ out) {
  const int l0  = blockIdx.x * 64;
  const int bo0 = blockIdx.y * 64;
  const int tid = threadIdx.x;
  __shared__ float t[64][65];

  const int boj = tid & 63, lq = tid >> 6;
#pragma unroll
  for (int rr = 0; rr < 16; ++rr) {
    const int li = rr * 4 + lq;
    const int l  = l0 + li;
    if (l < OLEN) t[li][boj] = tmp[(size_t)l * (BATCH * OCH) + bo0 + boj];
  }
  __syncthreads();
  const int lj = tid & 63, bq = tid >> 6;
  const int l  = l0 + lj;
#pragma unroll
  for (int rr = 0; rr < 16; ++rr) {
    const int bl = rr * 4 + bq;
    const int bo = bo0 + bl;
    if (l < OLEN) {
      const int oc = bo & (OCH - 1);
      out[(size_t)bo * OLEN + l] = t[lj][bl] + bias[oc * OLEN + l];
    }
  }
}

// fallback: naive fp32 (only if ws unexpectedly tiny)
__global__ void lc1d_naive(const float* __restrict__ x, const float* __restrict__ w,
                           const float* __restrict__ bias, float* __restrict__ out) {
  const int l = blockIdx.x, o = blockIdx.y, b = threadIdx.x;
  const float* wr = w + ((size_t)l * OCH + o) * KDIM;
  const float* xr = x + (size_t)b * (IN_CH * ILEN);
  float s = 0.f;
  for (int i = 0; i < IN_CH; ++i)
#pragma unroll
    for (int k = 0; k < 8; ++k) s += xr[i * ILEN + l + k] * wr[i * 8 + k];
  out[((size_t)b * OCH + o) * OLEN + l] = s + bias[o * OLEN + l];
}

extern "C" void kernel_launch(void* const* d_in, const int* in_sizes, int n_in,
                              void* d_out, int out_size, void* d_ws, size_t ws_size,
                              hipStream_t stream) {
  const float* x    = (const float*)d_in[0];
  const float* w    = (const float*)d_in[1];
  const float* bias = (const float*)d_in[2];
  float* out        = (float*)d_out;

  const size_t TMPB = (size_t)OLEN * BATCH * OCH * sizeof(float);   // 16.5 MB
  const size_t off1 = (TMPB + 255) & ~(size_t)255;
  const size_t XBB  = (size_t)BATCH * IN_CH * ILEN * sizeof(short); // 8.4 MB
  const size_t need = off1 + 2 * XBB;

  if (ws_size >= need) {
    float* tmp = (float*)d_ws;
    unsigned short* xbe = (unsigned short*)((char*)d_ws + off1);
    unsigned short* xbo = (unsigned short*)((char*)d_ws + off1 + XBB);
    lc1d_cvt<<<dim3(2048), 256, 0, stream>>>(x, xbe, xbo);
    lc1d_main<true><<<dim3(NWG), 256, 0, stream>>>(xbe, xbo, w, bias, tmp);
    lc1d_tr<<<dim3(8, 128), 256, 0, stream>>>(tmp, bias, out);
  } else {
    lc1d_naive<<<dim3(OLEN, OCH), BATCH, 0, stream>>>(x, w, bias, out);
  }
}

// Round 13
// 113.093 us; speedup vs baseline: 1.3235x; 1.3235x over previous
//
#include <hip/hip_runtime.h>
#include <hip/hip_bf16.h>

#define BATCH 64
#define IN_CH 128
#define ILEN  512
#define OLEN  505
#define OCH   128
#define KDIM  1024    // IN_CH * 8
#define BK    64      // K per chunk
#define NCHK  16      // KDIM / BK
#define NWG   OLEN

typedef float  f32x4  __attribute__((ext_vector_type(4)));
typedef short  bf16x8 __attribute__((ext_vector_type(8)));
typedef unsigned short u16x8 __attribute__((ext_vector_type(8)));
typedef u16x8 u16x8a __attribute__((aligned(4)));

__device__ __forceinline__ unsigned short f2bf(float f) {
  union { __hip_bfloat16 h; unsigned short s; } u;
  u.h = __float2bfloat16(f);
  return u.s;
}

// ---- pre-pass: x fp32 -> bf16 dual-shifted copies (R11-verified) ----
__global__ __launch_bounds__(256) void lc1d_cvt(const float* __restrict__ x,
                                                unsigned short* __restrict__ xbe,
                                                unsigned short* __restrict__ xbo) {
  const int gid = blockIdx.x * 256 + threadIdx.x;
  const int row = gid >> 6;
  const int t8  = (gid & 63) << 3;
  const float* src = x + (size_t)row * ILEN + t8;
  const f32x4 v0 = *reinterpret_cast<const f32x4*>(src);
  const f32x4 v1 = *reinterpret_cast<const f32x4*>(src + 4);
  const float e8 = (t8 + 8 < ILEN) ? src[8] : 0.f;
  u16x8 e, o;
#pragma unroll
  for (int j = 0; j < 4; ++j) { e[j] = f2bf(v0[j]); e[4 + j] = f2bf(v1[j]); }
  o[0] = e[1]; o[1] = e[2]; o[2] = e[3];
  o[3] = e[4]; o[4] = e[5]; o[5] = e[6]; o[6] = e[7];
  o[7] = f2bf(e8);
  *reinterpret_cast<u16x8*>(xbe + (size_t)row * ILEN + t8) = e;
  *reinterpret_cast<u16x8*>(xbo + (size_t)row * ILEN + t8) = o;
}

// ---- main: ALL-bf16 LDS. B reg-staged (coalesced f32x4 -> cvt -> b128),
// 2-ahead reg ring; A 1-ahead (R11 slim). 48KB LDS -> 3 blocks/CU.
// Consume: 12 ds_read_b128 + 16 MFMA, ZERO cvt. vmcnt never drained:
// barrier = lgkmcnt(0)+s_barrier only; compiler's register-dep waits give
// exact counted vmcnt (FIFO: A2 young -> vmcnt(8), B8 keeps flying 1 iter).
template <bool USE_TMP>
__global__ __launch_bounds__(256, 3) void lc1d_main(
    const unsigned short* __restrict__ xbe, const unsigned short* __restrict__ xbo,
    const float* __restrict__ w, const float* __restrict__ bias,
    float* __restrict__ outp) {
  const int orig = blockIdx.x;
  const int xcd = orig & 7, idx = orig >> 3;
  const int q = NWG / 8, rm = NWG % 8;
  const int l = (xcd < rm ? xcd * (q + 1) : rm * (q + 1) + (xcd - rm) * q) + idx;

  const int tid  = threadIdx.x;
  const int lane = tid & 63;
  const int wn   = tid >> 6;
  const int r    = lane & 15;
  const int h    = lane >> 4;

  __shared__ short Bs[2][OCH * BK];   // 32 KB: [o][k] bf16, chunk c'=c^(o&7)
  __shared__ short As[2][BATCH * BK]; // 16 KB: [b][k] bf16, chunk c'=c^(b&7)

  f32x4 acc[2][4];
#pragma unroll
  for (int oh = 0; oh < 2; ++oh)
#pragma unroll
    for (int m = 0; m < 4; ++m) acc[oh][m] = (f32x4){0.f, 0.f, 0.f, 0.f};

  const float* __restrict__ wl = w + (size_t)l * (OCH * KDIM);
  const unsigned short* __restrict__ xw =
      ((l & 1) ? xbo : xbe) + (size_t)(l & ~1);

  // ---- A staging (R11-verified): bA row, chunks iw*2, iw*2+1 ----
  const int bA = tid & 63;
  const int iw = tid >> 6;
  u16x8 va, vb;
  auto loadA = [&](int kc) {
    const unsigned short* p = xw + (size_t)(bA * IN_CH + kc * 8 + iw * 2) * ILEN;
    va = *reinterpret_cast<const u16x8a*>(p);
    vb = *reinterpret_cast<const u16x8a*>(p + ILEN);
  };
  auto writeA = [&](int buf) {
    const int c0 = iw * 2;
    *reinterpret_cast<u16x8*>(&As[buf][bA * 64 + ((c0 ^ (bA & 7)) << 3)]) = va;
    *reinterpret_cast<u16x8*>(&As[buf][bA * 64 + (((c0 + 1) ^ (bA & 7)) << 3)]) = vb;
  };

  // ---- B staging: thread -> (sc3 = 8-float chunk, soB = o-row), it x4 ----
  const int sc3 = tid & 7;
  const int soB = tid >> 3;          // 0..31
  f32x4 bb0[4][2], bb1[4][2];        // 2-ahead parity ring (64 VGPR)
  auto loadB = [&](f32x4 (&bb)[4][2], int kc) {
#pragma unroll
    for (int it = 0; it < 4; ++it) {
      const int o = it * 32 + soB;
      const float* src = wl + (size_t)o * KDIM + kc * BK + sc3 * 8;
      bb[it][0] = *reinterpret_cast<const f32x4*>(src);
      bb[it][1] = *reinterpret_cast<const f32x4*>(src + 4);
    }
  };
  auto writeB = [&](const f32x4 (&bb)[4][2], int buf) {
#pragma unroll
    for (int it = 0; it < 4; ++it) {
      const int o = it * 32 + soB;
      u16x8 v;
#pragma unroll
      for (int j = 0; j < 4; ++j) {
        v[j]     = f2bf(bb[it][0][j]);
        v[4 + j] = f2bf(bb[it][1][j]);
      }
      *reinterpret_cast<u16x8*>(&Bs[buf][o * 64 + ((sc3 ^ (o & 7)) << 3)]) = v;
    }
  };

  auto compute = [&](int cur, int oh) {
    const int ob = oh * 64 + wn * 16 + r;
#pragma unroll
    for (int ks = 0; ks < 2; ++ks) {
      const int c = ks * 4 + h;
      const bf16x8 bfr = *reinterpret_cast<const bf16x8*>(
          &Bs[cur][ob * 64 + ((c ^ (ob & 7)) << 3)]);
#pragma unroll
      for (int mt = 0; mt < 4; ++mt) {
        const int b = mt * 16 + r;
        const bf16x8 afr = *reinterpret_cast<const bf16x8*>(
            &As[cur][b * 64 + ((c ^ (b & 7)) << 3)]);
        acc[oh][mt] =
            __builtin_amdgcn_mfma_f32_16x16x32_bf16(afr, bfr, acc[oh][mt], 0, 0, 0);
      }
    }
  };

  // ---- prologue: A(0),B(0) -> LDS buf0; B(1) -> bb1 (flying) ----
  loadA(0);                // A2 (oldest)
  loadB(bb0, 0);           // B8(0)
  loadB(bb1, 1);           // B8(1)
  writeA(0);               // compiler waits vmcnt(16): A2 retired
  writeB(bb0, 0);          // compiler waits vmcnt(8): B8(0) retired; B8(1) flies
  asm volatile("s_waitcnt lgkmcnt(0)" ::: "memory");
  __builtin_amdgcn_sched_barrier(0);
  __builtin_amdgcn_s_barrier();
  __builtin_amdgcn_sched_barrier(0);

#pragma unroll
  for (int kc = 0; kc < NCHK; ++kc) {
    const int cur = kc & 1, nxt = cur ^ 1;
    // issue loads first: A(kc+1) older than B(kc+2) -> writeA waits only A
    if (kc + 1 < NCHK) loadA(kc + 1);
    if (kc + 2 < NCHK) {
      if ((kc & 1) == 0) loadB(bb0, kc + 2); else loadB(bb1, kc + 2);
    }
    __builtin_amdgcn_sched_barrier(0);
    compute(cur, 0);
    compute(cur, 1);
    if (kc + 1 < NCHK) {
      writeA(nxt);                                   // vmcnt: retire A2 only
      if ((kc & 1) == 0) writeB(bb1, nxt); else writeB(bb0, nxt);  // B(kc+1), reg-dep wait
      asm volatile("s_waitcnt lgkmcnt(0)" ::: "memory");  // NO vmcnt drain
      __builtin_amdgcn_sched_barrier(0);
      __builtin_amdgcn_s_barrier();
      __builtin_amdgcn_sched_barrier(0);
    }
  }

  // ---- epilogue (R8-verified): C/D col(o)=lane&15, row(b)=(lane>>4)*4+j ----
#pragma unroll
  for (int oh = 0; oh < 2; ++oh) {
    const int og = oh * 64 + wn * 16 + r;
    if (USE_TMP) {
      float* t = outp + (size_t)l * (BATCH * OCH) + og;
#pragma unroll
      for (int mt = 0; mt < 4; ++mt)
#pragma unroll
        for (int j = 0; j < 4; ++j) {
          const int b = mt * 16 + h * 4 + j;
          t[(size_t)b * OCH] = acc[oh][mt][j];
        }
    } else {
      const float bv = bias[og * OLEN + l];
#pragma unroll
      for (int mt = 0; mt < 4; ++mt)
#pragma unroll
        for (int j = 0; j < 4; ++j) {
          const int b = mt * 16 + h * 4 + j;
          outp[(size_t)b * (OCH * OLEN) + (size_t)og * OLEN + l] = acc[oh][mt][j] + bv;
        }
    }
  }
}

// tmp[l][b][o] -> out[b][o][l] (+bias)
__global__ __launch_bounds__(256) void lc1d_tr(const float* __restrict__ tmp,
                                               const float* __restrict__ bias,
                                               float* __restrict__ out) {
  const int l0  = blockIdx.x * 64;
  const int bo0 = blockIdx.y * 64;
  const int tid = threadIdx.x;
  __shared__ float t[64][65];

  const int boj = tid & 63, lq = tid >> 6;
#pragma unroll
  for (int rr = 0; rr < 16; ++rr) {
    const int li = rr * 4 + lq;
    const int l  = l0 + li;
    if (l < OLEN) t[li][boj] = tmp[(size_t)l * (BATCH * OCH) + bo0 + boj];
  }
  __syncthreads();
  const int lj = tid & 63, bq = tid >> 6;
  const int l  = l0 + lj;
#pragma unroll
  for (int rr = 0; rr < 16; ++rr) {
    const int bl = rr * 4 + bq;
    const int bo = bo0 + bl;
    if (l < OLEN) {
      const int oc = bo & (OCH - 1);
      out[(size_t)bo * OLEN + l] = t[lj][bl] + bias[oc * OLEN + l];
    }
  }
}

// fallback: naive fp32 (only if ws unexpectedly tiny)
__global__ void lc1d_naive(const float* __restrict__ x, const float* __restrict__ w,
                           const float* __restrict__ bias, float* __restrict__ out) {
  const int l = blockIdx.x, o = blockIdx.y, b = threadIdx.x;
  const float* wr = w + ((size_t)l * OCH + o) * KDIM;
  const float* xr = x + (size_t)b * (IN_CH * ILEN);
  float s = 0.f;
  for (int i = 0; i < IN_CH; ++i)
#pragma unroll
    for (int k = 0; k < 8; ++k) s += xr[i * ILEN + l + k] * wr[i * 8 + k];
  out[((size_t)b * OCH + o) * OLEN + l] = s + bias[o * OLEN + l];
}

extern "C" void kernel_launch(void* const* d_in, const int* in_sizes, int n_in,
                              void* d_out, int out_size, void* d_ws, size_t ws_size,
                              hipStream_t stream) {
  const float* x    = (const float*)d_in[0];
  const float* w    = (const float*)d_in[1];
  const float* bias = (const float*)d_in[2];
  float* out        = (float*)d_out;

  const size_t TMPB = (size_t)OLEN * BATCH * OCH * sizeof(float);   // 16.5 MB
  const size_t off1 = (TMPB + 255) & ~(size_t)255;
  const size_t XBB  = (size_t)BATCH * IN_CH * ILEN * sizeof(short); // 8.4 MB
  const size_t need = off1 + 2 * XBB;

  if (ws_size >= need) {
    float* tmp = (float*)d_ws;
    unsigned short* xbe = (unsigned short*)((char*)d_ws + off1);
    unsigned short* xbo = (unsigned short*)((char*)d_ws + off1 + XBB);
    lc1d_cvt<<<dim3(2048), 256, 0, stream>>>(x, xbe, xbo);
    lc1d_main<true><<<dim3(NWG), 256, 0, stream>>>(xbe, xbo, w, bias, tmp);
    lc1d_tr<<<dim3(8, 128), 256, 0, stream>>>(tmp, bias, out);
  } else {
    lc1d_naive<<<dim3(OLEN, OCH), BATCH, 0, stream>>>(x, w, bias, out);
  }
}

// Round 14
// 93.282 us; speedup vs baseline: 1.6046x; 1.2124x over previous
//
#include <hip/hip_runtime.h>
#include <hip/hip_bf16.h>

#define BATCH 64
#define IN_CH 128
#define ILEN  512
#define OLEN  505
#define OCH   128
#define KDIM  1024    // IN_CH * 8
#define BK    64      // K per chunk
#define NCHK  16      // KDIM / BK
#define NWG   OLEN

typedef float  f32x4  __attribute__((ext_vector_type(4)));
typedef short  bf16x8 __attribute__((ext_vector_type(8)));

__device__ __forceinline__ unsigned short f2bfu(float f) {
  union { __hip_bfloat16 h; unsigned short s; } u;
  u.h = __float2bfloat16(f);
  return u.s;
}
__device__ __forceinline__ short f2bf(float f) { return (short)f2bfu(f); }
__device__ __forceinline__ float bf2f(unsigned short s) {
  union { unsigned int u; float f; } u;
  u.u = ((unsigned int)s) << 16;
  return u.f;
}

// ============ MAIN: R8 base + compressed consume burst + bf16 tmp ============
// R8-verified: staging maps, swizzles, vmcnt schedule, barriers, C/D layout.
// NEW (burst theory): per ks, ALL unique LDS reads (4 afr + 4 B-words) are
// issued first into regs (R8 read the same afr twice, 24 b128/thread; now 16),
// then a pure-MFMA stretch leaves the DS pipe free for the in-flight
// global_load_lds DMA writes to land -> vmcnt(16) wait no longer stalls.
template <bool USE_TMP>
__global__ __launch_bounds__(256, 2) void lc1d_main(
    const float* __restrict__ x, const float* __restrict__ w,
    const float* __restrict__ bias, void* __restrict__ outp) {
  const int orig = blockIdx.x;
  const int xcd = orig & 7, idx = orig >> 3;
  const int q = NWG / 8, rm = NWG % 8;
  const int l = (xcd < rm ? xcd * (q + 1) : rm * (q + 1) + (xcd - rm) * q) + idx;

  const int tid  = threadIdx.x;
  const int lane = tid & 63;
  const int wn   = tid >> 6;
  const int r    = lane & 15;
  const int h    = lane >> 4;

  __shared__ float Bs[2][2][BK * 64];
  __shared__ short As[2][BK * 64];

  f32x4 acc[2][4];
#pragma unroll
  for (int oh = 0; oh < 2; ++oh)
#pragma unroll
    for (int m = 0; m < 4; ++m) acc[oh][m] = (f32x4){0.f, 0.f, 0.f, 0.f};

  const float* __restrict__ wl = w + (size_t)l * (OCH * KDIM);

  const int so  = tid >> 4;
  const int sc  = tid & 15;
  const int ssw = ((so & 7) << 1) | ((so >> 3) & 1);

  const int kk  = tid & 63;
  const int tb  = tid >> 6;
  const int il  = kk >> 3;
  const int kof = kk & 7;

  float aa0[16], aa1[16];

  auto loadA = [&](float (&aa)[16], int kc) {
    const float* xb = x + (size_t)(kc * 8 + il) * ILEN + l + kof;
#pragma unroll
    for (int it = 0; it < 16; ++it)
      aa[it] = xb[(size_t)(it * 4 + tb) * (IN_CH * ILEN)];
  };
  auto writeA = [&](const float (&aa)[16], int buf) {
#pragma unroll
    for (int it = 0; it < 16; ++it) {
      const int b = it * 4 + tb;
      As[buf][b * 64 + (kk ^ ((b & 7) << 3))] = f2bf(aa[it]);
    }
  };
  auto stageB = [&](int buf, int kc, int oh) {
    const float* wo = wl + (size_t)oh * 64 * KDIM;
#pragma unroll
    for (int it = 0; it < 4; ++it) {
      const int ob = it * 16 + so;
      const float* src = wo + (size_t)ob * KDIM + kc * BK + (sc ^ ssw) * 4;
      __builtin_amdgcn_global_load_lds(
          (const __attribute__((address_space(1))) void*)src,
          (__attribute__((address_space(3))) void*)&Bs[buf][oh][ob * 64 + sc * 4],
          16, 0, 0);
    }
  };

  const int rsw = ((r & 7) << 1) | ((r >> 3) & 1);
  // consume both oh halves; per ks: batched reads -> pure MFMA stretch
  auto computeBoth = [&](int cur) {
    const int ob = wn * 16 + r;
#pragma unroll
    for (int ks = 0; ks < 2; ++ks) {
      const int c0 = ks * 8 + h * 2;
      // ---- batched unique LDS reads (8 x b128) ----
      bf16x8 af[4];
#pragma unroll
      for (int mt = 0; mt < 4; ++mt) {
        const int b = mt * 16 + r;
        af[mt] = *reinterpret_cast<const bf16x8*>(
            &As[cur][b * 64 + ((ks * 32 + h * 8) ^ ((b & 7) << 3))]);
      }
      const f32x4 b0lo = *reinterpret_cast<const f32x4*>(
          &Bs[cur][0][ob * 64 + ((c0) ^ rsw) * 4]);
      const f32x4 b0hi = *reinterpret_cast<const f32x4*>(
          &Bs[cur][0][ob * 64 + ((c0 + 1) ^ rsw) * 4]);
      const f32x4 b1lo = *reinterpret_cast<const f32x4*>(
          &Bs[cur][1][ob * 64 + ((c0) ^ rsw) * 4]);
      const f32x4 b1hi = *reinterpret_cast<const f32x4*>(
          &Bs[cur][1][ob * 64 + ((c0 + 1) ^ rsw) * 4]);
      bf16x8 bf0, bf1;
#pragma unroll
      for (int j = 0; j < 4; ++j) {
        bf0[j] = f2bf(b0lo[j]); bf0[4 + j] = f2bf(b0hi[j]);
        bf1[j] = f2bf(b1lo[j]); bf1[4 + j] = f2bf(b1hi[j]);
      }
      // ---- pure MFMA stretch (DS pipe free for DMA landing) ----
#pragma unroll
      for (int mt = 0; mt < 4; ++mt)
        acc[0][mt] = __builtin_amdgcn_mfma_f32_16x16x32_bf16(af[mt], bf0, acc[0][mt], 0, 0, 0);
#pragma unroll
      for (int mt = 0; mt < 4; ++mt)
        acc[1][mt] = __builtin_amdgcn_mfma_f32_16x16x32_bf16(af[mt], bf1, acc[1][mt], 0, 0, 0);
    }
  };

  // ---- prologue (R8-verbatim) ----
  loadA(aa0, 0);
  stageB(0, 0, 0);
  stageB(0, 0, 1);
  writeA(aa0, 0);
  loadA(aa1, 1);
  asm volatile("s_waitcnt vmcnt(16) lgkmcnt(0)" ::: "memory");
  __builtin_amdgcn_sched_barrier(0);
  __builtin_amdgcn_s_barrier();
  __builtin_amdgcn_sched_barrier(0);

  auto step = [&](int kc, float (&aaW)[16], float (&aaL)[16]) {
    if (kc + 1 < NCHK) {
      const int nxt = (kc + 1) & 1;
      stageB(nxt, kc + 1, 0);
      stageB(nxt, kc + 1, 1);
    }
    if (kc + 2 < NCHK) loadA(aaL, kc + 2);
    __builtin_amdgcn_sched_barrier(0);
    computeBoth(kc & 1);
    if (kc + 1 < NCHK) {
      writeA(aaW, (kc + 1) & 1);
      if (kc + 2 < NCHK) {
        asm volatile("s_waitcnt vmcnt(16) lgkmcnt(0)" ::: "memory");
      } else {
        asm volatile("s_waitcnt vmcnt(0) lgkmcnt(0)" ::: "memory");
      }
      __builtin_amdgcn_sched_barrier(0);
      __builtin_amdgcn_s_barrier();
      __builtin_amdgcn_sched_barrier(0);
    }
  };

  for (int kc = 0; kc < NCHK; kc += 2) {
    step(kc, aa1, aa0);
    step(kc + 1, aa0, aa1);
  }

  // ---- epilogue: C/D col(o)=lane&15, row(b)=(lane>>4)*4+j ----
#pragma unroll
  for (int oh = 0; oh < 2; ++oh) {
    const int og = oh * 64 + wn * 16 + r;
    if (USE_TMP) {
      unsigned short* t = (unsigned short*)outp + (size_t)l * (BATCH * OCH) + og;
#pragma unroll
      for (int mt = 0; mt < 4; ++mt)
#pragma unroll
        for (int j = 0; j < 4; ++j) {
          const int b = mt * 16 + h * 4 + j;
          t[(size_t)b * OCH] = f2bfu(acc[oh][mt][j]);   // bf16 tmp (halved bytes)
        }
    } else {
      const float bv = bias[og * OLEN + l];
#pragma unroll
      for (int mt = 0; mt < 4; ++mt)
#pragma unroll
        for (int j = 0; j < 4; ++j) {
          const int b = mt * 16 + h * 4 + j;
          ((float*)outp)[(size_t)b * (OCH * OLEN) + (size_t)og * OLEN + l] =
              acc[oh][mt][j] + bv;
        }
    }
  }
}

// tmp(bf16)[l][b][o] -> out(f32)[b][o][l] (+bias), 64x64 LDS tile transpose
__global__ __launch_bounds__(256) void lc1d_tr(const unsigned short* __restrict__ tmp,
                                               const float* __restrict__ bias,
                                               float* __restrict__ out) {
  const int l0  = blockIdx.x * 64;
  const int bo0 = blockIdx.y * 64;
  const int tid = threadIdx.x;
  __shared__ float t[64][65];

  const int boj = tid & 63, lq = tid >> 6;
#pragma unroll
  for (int rr = 0; rr < 16; ++rr) {
    const int li = rr * 4 + lq;
    const int l  = l0 + li;
    if (l < OLEN)
      t[li][boj] = bf2f(tmp[(size_t)l * (BATCH * OCH) + bo0 + boj]);
  }
  __syncthreads();
  const int lj = tid & 63, bq = tid >> 6;
  const int l  = l0 + lj;
#pragma unroll
  for (int rr = 0; rr < 16; ++rr) {
    const int bl = rr * 4 + bq;
    const int bo = bo0 + bl;
    if (l < OLEN) {
      const int oc = bo & (OCH - 1);
      out[(size_t)bo * OLEN + l] = t[lj][bl] + bias[oc * OLEN + l];
    }
  }
}

extern "C" void kernel_launch(void* const* d_in, const int* in_sizes, int n_in,
                              void* d_out, int out_size, void* d_ws, size_t ws_size,
                              hipStream_t stream) {
  const float* x    = (const float*)d_in[0];
  const float* w    = (const float*)d_in[1];
  const float* bias = (const float*)d_in[2];
  float* out        = (float*)d_out;

  const size_t need = (size_t)OLEN * BATCH * OCH * sizeof(unsigned short);  // 8.3 MB
  if (ws_size >= need) {
    unsigned short* tmp = (unsigned short*)d_ws;
    lc1d_main<true><<<dim3(NWG), 256, 0, stream>>>(x, w, bias, (void*)tmp);
    lc1d_tr<<<dim3(8, 128), 256, 0, stream>>>(tmp, bias, out);
  } else {
    lc1d_main<false><<<dim3(NWG), 256, 0, stream>>>(x, w, bias, (void*)out);
  }
}